// Round 8
// baseline (577.201 us; speedup 1.0000x reference)
//
#include <hip/hip_runtime.h>

// ---------------------------------------------------------------------------
// NodeTaskHead: B=8 N=256 M=512 EXT=768 E=1024 H=32 D=32
// R9: BARRIER-FREE fused_attn. R8 confirmed the kernel is drain-latency
// bound (12 vmcnt(0) drains x ~900cy each); pipeline schedules that hide it
// crash this harness (4/4). Fix: remove the reason the barrier exists.
// Every MFMA fragment (K, V^T streams, R) is loaded per-lane DIRECTLY from
// global in fragment layout (verified vs staged layouts); LDS keeps only the
// 5KB wave-private P-transpose. Zero __syncthreads in the k-loop; latency
// hiding = TLP (16 waves/CU, 21 indep loads/tile/wave) + free load hoisting.
// Redundant K/V/R fragment re-reads are absorbed by L2 (~1.5GB @ 34TB/s).
// Algorithm (R3 factorization, passing since Round 2):
//   sum_m p*r*(pos_nc - apos_mc)*v = pos_nc*(PR@V) - PR@(apos_c . V)
// Pipeline: convert -> proj GEMM -> shuffle -> scale_v -> prep_r ->
//           fused_attn -> final GEMM (merged).
// ---------------------------------------------------------------------------

typedef unsigned short u16;
typedef unsigned int u32;
typedef short short8 __attribute__((ext_vector_type(8)));
typedef float float4v __attribute__((ext_vector_type(4)));

#define SCALING 0.17677669529663687f
#define LOG2E 1.4426950408889634f

__device__ __forceinline__ u16 f2b(float f) {
  union { float f; u32 u; } v; v.f = f;
  return (u16)((v.u + 0x7FFFu + ((v.u >> 16) & 1u)) >> 16);
}
__device__ __forceinline__ float b2f(short s) {
  union { u32 u; float f; } v; v.u = ((u32)(u16)s) << 16;
  return v.f;
}
__device__ __forceinline__ float4v mfma16(short8 a, short8 b, float4v c) {
  return __builtin_amdgcn_mfma_f32_16x16x32_bf16(a, b, c, 0, 0, 0);
}
// async global->LDS, 16B per lane (gemm_bt only; proven passing)
__device__ __forceinline__ void gll16(const void* g, void* l) {
  __builtin_amdgcn_global_load_lds((const __attribute__((address_space(1))) void*)g,
                                   (__attribute__((address_space(3))) void*)l, 16, 0, 0);
}

// ---------------------------------------------------------------------------
// K1: dtype conversions.
// ---------------------------------------------------------------------------
__global__ __launch_bounds__(256) void convert_kernel(
    const float* __restrict__ x, const float* __restrict__ Wq,
    const float* __restrict__ Wk, const float* __restrict__ Wv,
    const float* __restrict__ Wve, const float* __restrict__ Wo,
    const float* __restrict__ Woe, u16* __restrict__ xb,
    u16* __restrict__ Wcat, u16* __restrict__ Woe_b, u16* __restrict__ Wo_b) {
  const int idx = blockIdx.x * 256 + threadIdx.x;
  const int stride = gridDim.x * 256;
  for (int i = idx; i < 2048 * 1024; i += stride) {
    const int row = i >> 10, e = i & 1023;
    const int b = row >> 8, n = row & 255;
    xb[i] = f2b(x[((size_t)n * 8 + b) * 1024 + e]);
  }
  for (int i = idx; i < 1024 * 1024; i += stride) {
    Wcat[i] = f2b(Wq[i]);
    Wcat[1048576 + i] = f2b(Wk[i]);
    Wcat[2097152 + i] = f2b(Wv[i]);
    Wcat[3145728 + i] = f2b(Wve[i]);
    Woe_b[i] = f2b(Woe[i]);
    Wo_b[i] = f2b(Wo[i]);
  }
}

// ---------------------------------------------------------------------------
// MFMA bf16 GEMM, C[M,N] f32 = A[M,K] @ W[N,K]^T (bf16 row-major).
// 128x128 tile / block. W selected per row-tile (merged epilogue GEMMs).
// ---------------------------------------------------------------------------
__global__ __launch_bounds__(256) void gemm_bt(
    const u16* __restrict__ A, const u16* __restrict__ W_lo,
    const u16* __restrict__ W_hi, int split_row, float* __restrict__ C,
    int Ndim, int Kdim) {
  __shared__ __align__(16) u16 sA[128 * 32];
  __shared__ __align__(16) u16 sB[128 * 32];
  const int tid = threadIdx.x, wave = tid >> 6, lane = tid & 63;
  const int quad = lane >> 4, l15 = lane & 15;
  const int row0 = blockIdx.y * 128, col0 = blockIdx.x * 128;
  const u16* W = (row0 < split_row) ? W_lo : W_hi;
  const int wr = (wave >> 1) * 64, wc = (wave & 1) * 64;
  const int sr = lane >> 2, sc = lane & 3;
  float4v acc[4][4] = {};
  const u16* gA = A + (size_t)row0 * Kdim;
  const u16* gW = W + (size_t)col0 * Kdim;
  for (int k0 = 0; k0 < Kdim; k0 += 32) {
    __syncthreads();
#pragma unroll
    for (int i = 0; i < 2; ++i) {
      const int r = wave * 32 + i * 16 + sr;
      gll16(gA + (size_t)r * Kdim + k0 + sc * 8, (char*)sA + (wave * 32 + i * 16) * 64);
      gll16(gW + (size_t)r * Kdim + k0 + sc * 8, (char*)sB + (wave * 32 + i * 16) * 64);
    }
    __syncthreads();
    short8 af[4], bf[4];
#pragma unroll
    for (int t = 0; t < 4; ++t) {
      af[t] = *(const short8*)(sA + (wr + t * 16 + l15) * 32 + quad * 8);
      bf[t] = *(const short8*)(sB + (wc + t * 16 + l15) * 32 + quad * 8);
    }
#pragma unroll
    for (int tm = 0; tm < 4; ++tm)
#pragma unroll
      for (int tn = 0; tn < 4; ++tn)
        acc[tm][tn] = mfma16(af[tm], bf[tn], acc[tm][tn]);
  }
#pragma unroll
  for (int tm = 0; tm < 4; ++tm)
#pragma unroll
    for (int tn = 0; tn < 4; ++tn)
#pragma unroll
      for (int r = 0; r < 4; ++r) {
        const int row = row0 + wr + tm * 16 + quad * 4 + r;
        const int col = col0 + wc + tn * 16 + l15;
        C[(size_t)row * Ndim + col] = acc[tm][tn][r];
      }
}

// ---------------------------------------------------------------------------
// K3: build per-head bf16 operands from proj [2048][4096] f32.
// ---------------------------------------------------------------------------
__global__ __launch_bounds__(256) void shuffle_kernel(
    const float* __restrict__ proj, const int* __restrict__ outcell,
    u16* __restrict__ qrow, u16* __restrict__ kext,
    u16* __restrict__ vTx, u16* __restrict__ veTx) {
  __shared__ float lds[32 * 129];
  const int mt = blockIdx.x, h = blockIdx.y, b = blockIdx.z;
  const int tid = threadIdx.x;
  const int bh = b * 32 + h;
#pragma unroll 4
  for (int i = 0; i < 16; ++i) {
    const int idx = tid + 256 * i;  // [128 m][32 d]
    const int ml = idx >> 5, d = idx & 31;
    const int m = mt * 128 + ml;
    const int src = (m < 256) ? m : outcell[b * 512 + m - 256];
    const size_t prow = ((size_t)b * 256 + src) * 4096;
    kext[((size_t)bh * 768 + m) * 32 + d] = f2b(proj[prow + 1024 + h * 32 + d]);
    if (m < 256)
      qrow[((size_t)bh * 256 + m) * 32 + d] = f2b(proj[prow + h * 32 + d] * SCALING);
  }
  for (int part = 0; part < 2; ++part) {
    const size_t cbase = (part == 0) ? 2048 : 3072;
    u16* dst = (part == 0) ? vTx : veTx;
    __syncthreads();
#pragma unroll 4
    for (int i = 0; i < 16; ++i) {
      const int idx = tid + 256 * i;
      const int ml = idx >> 5, d = idx & 31;
      const int m = mt * 128 + ml;
      const int src = (m < 256) ? m : outcell[b * 512 + m - 256];
      lds[d * 129 + ml] = proj[((size_t)b * 256 + src) * 4096 + cbase + h * 32 + d];
    }
    __syncthreads();
#pragma unroll 4
    for (int i = 0; i < 16; ++i) {
      const int idx = tid + 256 * i;
      const int d = idx >> 7, m2 = idx & 127;
      dst[((size_t)bh * 32 + d) * 768 + mt * 128 + m2] = f2b(lds[d * 129 + m2]);
    }
  }
}

// ---------------------------------------------------------------------------
// K3b: V'_c[bh][d][m] = apos[b][m][c] * vTx[bh][d][m]  (c = x,y,z).
// ---------------------------------------------------------------------------
__global__ __launch_bounds__(256) void scale_v_kernel(
    const u16* __restrict__ vTx, const float* __restrict__ pos,
    const float* __restrict__ epos, u16* __restrict__ v0,
    u16* __restrict__ v1, u16* __restrict__ v2) {
  const int bh = blockIdx.x, d = blockIdx.y, b = bh >> 5;
  const size_t base = ((size_t)bh * 32 + d) * 768;
  for (int m = threadIdx.x; m < 768; m += 256) {
    const float f = b2f((short)vTx[base + m]);
    const float* ap = (m < 256) ? (pos + ((size_t)b * 256 + m) * 3)
                                : (epos + ((size_t)b * 512 + (m - 256)) * 3);
    v0[base + m] = f2b(f * ap[0]);
    v1[base + m] = f2b(f * ap[1]);
    v2[base + m] = f2b(f * ap[2]);
  }
}

// ---------------------------------------------------------------------------
// K3c: R[b][n][m] = 1/(1 + |pos_bn - apos_bm|), bf16. Head-shared (3.1 MB).
// ---------------------------------------------------------------------------
__global__ __launch_bounds__(256) void prep_r_kernel(
    const float* __restrict__ pos, const float* __restrict__ epos,
    u16* __restrict__ R) {
  const int bn = blockIdx.x;  // 0..2047
  const int b = bn >> 8;
  const float px = pos[(size_t)bn * 3];
  const float py = pos[(size_t)bn * 3 + 1];
  const float pz = pos[(size_t)bn * 3 + 2];
  for (int m = threadIdx.x; m < 768; m += 256) {
    const float* ap = (m < 256) ? (pos + ((size_t)b * 256 + m) * 3)
                                : (epos + ((size_t)b * 512 + (m - 256)) * 3);
    const float dx = px - ap[0], dy = py - ap[1], dz = pz - ap[2];
    const float dist = __builtin_amdgcn_sqrtf(dx * dx + dy * dy + dz * dz);
    R[(size_t)bn * 768 + m] = f2b(__builtin_amdgcn_rcpf(1.0f + dist));
  }
}

// ---------------------------------------------------------------------------
// K4: fused attention, BARRIER-FREE. Grid (nt=4, bh=256); 4 waves x 16
// q-rows, each wave fully independent. Per 32-col tile: per-lane global
// loads of K/V/R fragments in MFMA layout + bias -> QK^T -> exp -> P
// transpose through wave-private LDS -> 12 PV MFMAs. No __syncthreads.
// ---------------------------------------------------------------------------
__global__ __launch_bounds__(256) void fused_attn(
    const u16* __restrict__ qrow, const u16* __restrict__ kext,
    const u16* __restrict__ vTx, const u16* __restrict__ veTx,
    const u16* __restrict__ v0Tx, const u16* __restrict__ v1Tx,
    const u16* __restrict__ v2Tx, const u16* __restrict__ Rmat,
    const float* __restrict__ bias, const float* __restrict__ pos,
    u16* __restrict__ xo_acc, u16* __restrict__ vec_acc) {
  __shared__ __align__(16) u16 sPT[4 * 16 * 40];  // wave-private P transpose
  const int nt = blockIdx.x, bh = blockIdx.y, b = bh >> 5, h = bh & 31;
  const int n0 = nt * 64;
  const int tid = threadIdx.x, w = tid >> 6, lane = tid & 63;
  const int quad = lane >> 4, l15 = lane & 15;
  // Q fragment (16B/lane, coalesced)
  const short8 qf =
      *(const short8*)(qrow + ((size_t)bh * 256 + n0 + w * 16 + l15) * 32 + quad * 8);
  float4v acc_e[2] = {}, acc_v[2] = {}, acc_c[3][2] = {};
  float rowsum[4] = {0.f, 0.f, 0.f, 0.f};
  // fragment base pointers (per-lane, advance by k each tile)
  const u16* gK = kext + (size_t)bh * (768 * 32);
  const u16* pV = vTx + (size_t)bh * (32 * 768) + (size_t)l15 * 768 + quad * 8;
  const u16* pVe = veTx + (size_t)bh * (32 * 768) + (size_t)l15 * 768 + quad * 8;
  const u16* pV0 = v0Tx + (size_t)bh * (32 * 768) + (size_t)l15 * 768 + quad * 8;
  const u16* pV1 = v1Tx + (size_t)bh * (32 * 768) + (size_t)l15 * 768 + quad * 8;
  const u16* pV2 = v2Tx + (size_t)bh * (32 * 768) + (size_t)l15 * 768 + quad * 8;
  const u16* pR = Rmat + ((size_t)b * 256 + n0 + w * 16 + l15) * 768 + quad * 8;
  const float* gB = bias + ((size_t)bh * 256 + n0 + w * 16) * 768;
  u16* const pt = sPT + w * 640;  // 16 rows x 40 u16, wave-private

  for (int k0 = 0; k0 < 768; k0 += 32) {
    // K A/B fragments: rows k0+l15 / k0+16+l15 (1KB contiguous per 16 rows)
    const short8 kf0 = *(const short8*)(gK + (size_t)(k0 + l15) * 32 + quad * 8);
    const short8 kf1 = *(const short8*)(gK + (size_t)(k0 + 16 + l15) * 32 + quad * 8);
    // bias in C-frag layout (per-lane dwords)
    float bb[4][2];
#pragma unroll
    for (int r = 0; r < 4; ++r) {
      const float* bp = gB + (size_t)(quad * 4 + r) * 768 + k0;
      bb[r][0] = bp[l15];
      bb[r][1] = bp[16 + l15];
    }
    float4v z = {0.f, 0.f, 0.f, 0.f};
    const float4v s0 = mfma16(qf, kf0, z);
    const float4v s1 = mfma16(qf, kf1, z);
#pragma unroll
    for (int r = 0; r < 4; ++r) {
      const int row = quad * 4 + r;
      const float p0 = exp2f((s0[r] + bb[r][0]) * LOG2E);
      const float p1 = exp2f((s1[r] + bb[r][1]) * LOG2E);
      rowsum[r] += p0 + p1;
      pt[row * 40 + l15] = f2b(p0);
      pt[row * 40 + 16 + l15] = f2b(p1);
    }
    // read back as A-frag (same-wave LDS, lgkm-ordered)
    const short8 pf = *(const short8*)(pt + l15 * 40 + quad * 8);
    // R fragment: row n0+w*16+l15, cols k0+quad*8 (per-lane 16B)
    const short8 rf = *(const short8*)(pR + k0);
    short8 prf;
#pragma unroll
    for (int j = 0; j < 8; ++j)
      prf[j] = (short)f2b(b2f(pf[j]) * b2f(rf[j]));
    // PV: B-fragments straight from global (row d = dt*16+l15, cols k0+quad*8)
#pragma unroll
    for (int dt = 0; dt < 2; ++dt) {
      const size_t off = (size_t)dt * 16 * 768 + k0;
      const short8 be = *(const short8*)(pVe + off);
      acc_e[dt] = mfma16(pf, be, acc_e[dt]);
      const short8 bv = *(const short8*)(pV + off);
      acc_v[dt] = mfma16(prf, bv, acc_v[dt]);
      const short8 c0 = *(const short8*)(pV0 + off);
      acc_c[0][dt] = mfma16(prf, c0, acc_c[0][dt]);
      const short8 c1 = *(const short8*)(pV1 + off);
      acc_c[1][dt] = mfma16(prf, c1, acc_c[1][dt]);
      const short8 c2 = *(const short8*)(pV2 + off);
      acc_c[2][dt] = mfma16(prf, c2, acc_c[2][dt]);
    }
  }

  // complete row sums (reduce over the 16 lanes of each quad-row group)
  float li[4];
#pragma unroll
  for (int r = 0; r < 4; ++r) {
    float s = rowsum[r];
#pragma unroll
    for (int msk = 1; msk < 16; msk <<= 1) s += __shfl_xor(s, msk, 64);
    li[r] = __builtin_amdgcn_rcpf(s);
  }
#pragma unroll
  for (int r = 0; r < 4; ++r) {
    const int row = n0 + w * 16 + quad * 4 + r;
    const size_t prow = ((size_t)b * 256 + row) * 3;
    const float pxr = pos[prow], pyr = pos[prow + 1], pzr = pos[prow + 2];
#pragma unroll
    for (int dt = 0; dt < 2; ++dt) {
      const int col = dt * 16 + l15;
      xo_acc[((size_t)b * 256 + row) * 1024 + h * 32 + col] =
          f2b(acc_e[dt][r] * li[r]);
      const float vx = (pxr * acc_v[dt][r] - acc_c[0][dt][r]) * li[r];
      const float vy = (pyr * acc_v[dt][r] - acc_c[1][dt][r]) * li[r];
      const float vz = (pzr * acc_v[dt][r] - acc_c[2][dt][r]) * li[r];
      vec_acc[(prow + 0) * 1024 + h * 32 + col] = f2b(vx);
      vec_acc[(prow + 1) * 1024 + h * 32 + col] = f2b(vy);
      vec_acc[(prow + 2) * 1024 + h * 32 + col] = f2b(vz);
    }
  }
}

// ---------------------------------------------------------------------------
// Workspace layout (bytes). Footprint unchanged (109,051,904 B):
// V'0 aliases xb+Wcat (dead after proj GEMM); V'1/V'2/R alias proj (dead
// after shuffle). scale_v/prep_r therefore launch AFTER shuffle.
// ---------------------------------------------------------------------------
static constexpr size_t OFF_XB = 0;                          // 2048*1024*2
static constexpr size_t OFF_WCAT = OFF_XB + 4194304;         // 4096*1024*2
static constexpr size_t OFF_WOEB = OFF_WCAT + 8388608;       // 1024*1024*2
static constexpr size_t OFF_WOB = OFF_WOEB + 2097152;        // 1024*1024*2
static constexpr size_t OFF_PROJ = OFF_WOB + 2097152;        // 2048*4096*4
static constexpr size_t OFF_QROW = OFF_PROJ + 33554432;      // 256bh*256*32*2
static constexpr size_t OFF_KEXT = OFF_QROW + 4194304;       // 256bh*768*32*2
static constexpr size_t OFF_VTX = OFF_KEXT + 12582912;
static constexpr size_t OFF_VETX = OFF_VTX + 12582912;
static constexpr size_t OFF_XOACC = OFF_VETX + 12582912;     // 2048*1024*2
static constexpr size_t OFF_VECACC = OFF_XOACC + 4194304;    // 6144*1024*2
// aliased regions:
static constexpr size_t OFF_V0 = OFF_XB;                     // 12,582,912
static constexpr size_t OFF_V1 = OFF_PROJ;                   // 12,582,912
static constexpr size_t OFF_V2 = OFF_PROJ + 12582912;        // 12,582,912
static constexpr size_t OFF_R = OFF_PROJ + 25165824;         // 2048*768*2

extern "C" void kernel_launch(void* const* d_in, const int* in_sizes, int n_in,
                              void* d_out, int out_size, void* d_ws, size_t ws_size,
                              hipStream_t stream) {
  const float* x = (const float*)d_in[0];
  const float* pos = (const float*)d_in[1];
  const float* epos = (const float*)d_in[2];
  const float* bias = (const float*)d_in[3];
  const int* outcell = (const int*)d_in[6];
  const float* Wq = (const float*)d_in[7];
  const float* Wk = (const float*)d_in[8];
  const float* Wv = (const float*)d_in[9];
  const float* Wve = (const float*)d_in[10];
  const float* Wo = (const float*)d_in[11];
  const float* Woe = (const float*)d_in[12];
  char* ws = (char*)d_ws;
  u16* xb = (u16*)(ws + OFF_XB);
  u16* Wcat = (u16*)(ws + OFF_WCAT);
  u16* Woe_b = (u16*)(ws + OFF_WOEB);
  u16* Wo_b = (u16*)(ws + OFF_WOB);
  float* proj = (float*)(ws + OFF_PROJ);
  u16* qrow = (u16*)(ws + OFF_QROW);
  u16* kext = (u16*)(ws + OFF_KEXT);
  u16* vTx = (u16*)(ws + OFF_VTX);
  u16* veTx = (u16*)(ws + OFF_VETX);
  u16* v0 = (u16*)(ws + OFF_V0);
  u16* v1 = (u16*)(ws + OFF_V1);
  u16* v2 = (u16*)(ws + OFF_V2);
  u16* Rm = (u16*)(ws + OFF_R);
  u16* xo_acc = (u16*)(ws + OFF_XOACC);
  u16* vec_acc = (u16*)(ws + OFF_VECACC);
  float* out = (float*)d_out;

  convert_kernel<<<1024, 256, 0, stream>>>(x, Wq, Wk, Wv, Wve, Wo, Woe,
                                           xb, Wcat, Woe_b, Wo_b);
  gemm_bt<<<dim3(32, 16), 256, 0, stream>>>(xb, Wcat, Wcat, 1 << 30, proj, 4096, 1024);
  shuffle_kernel<<<dim3(6, 32, 8), 256, 0, stream>>>(proj, outcell, qrow, kext, vTx, veTx);
  scale_v_kernel<<<dim3(256, 32), 256, 0, stream>>>(vTx, pos, epos, v0, v1, v2);
  prep_r_kernel<<<2048, 256, 0, stream>>>(pos, epos, Rm);
  fused_attn<<<dim3(4, 256), 256, 0, stream>>>(qrow, kext, vTx, veTx, v0, v1, v2,
                                               Rm, bias, pos, xo_acc, vec_acc);
  gemm_bt<<<dim3(8, 64), 256, 0, stream>>>(xo_acc, Woe_b, Wo_b, 2048, out, 1024, 1024);
}

// Round 10
// 463.525 us; speedup vs baseline: 1.2452x; 1.2452x over previous
//
#include <hip/hip_runtime.h>

// ---------------------------------------------------------------------------
// NodeTaskHead: B=8 N=256 M=512 EXT=768 E=1024 H=32 D=32
// R11 = R10 resubmit, byte-identical kernel (acquire-layer "container failed
// twice" has precedent of hitting known-good kernels: R1->R2; audit of the
// swizzle algebra, coverage, bounds, and sync structure found no defect).
// R10 = R8 skeleton (barrier -> stage -> barrier -> compute) + two fixes:
//  (a) XOR-swizzle (unit ^= row&7) on 128B-row tiles (sV*,sR): linear gll16
//      dest + pre-swizzled per-lane GLOBAL source + same XOR on ds_read.
//  (b) 128 q-rows per block (2 row-groups per wave): stage bytes per output
//      halved; per-CU drains 48 -> 24. Grid (2,256), LDS 45KB, 2 blocks/CU.
// Algorithm (R3 factorization, passing since Round 2):
//   sum_m p*r*(pos_nc - apos_mc)*v = pos_nc*(PR@V) - PR@(apos_c . V)
// Pipeline: convert -> proj GEMM -> shuffle -> scale_v -> prep_r ->
//           fused_attn -> final GEMM (merged).
// ---------------------------------------------------------------------------

typedef unsigned short u16;
typedef unsigned int u32;
typedef short short8 __attribute__((ext_vector_type(8)));
typedef float float4v __attribute__((ext_vector_type(4)));

#define SCALING 0.17677669529663687f
#define LOG2E 1.4426950408889634f

__device__ __forceinline__ u16 f2b(float f) {
  union { float f; u32 u; } v; v.f = f;
  return (u16)((v.u + 0x7FFFu + ((v.u >> 16) & 1u)) >> 16);
}
__device__ __forceinline__ float b2f(short s) {
  union { u32 u; float f; } v; v.u = ((u32)(u16)s) << 16;
  return v.f;
}
__device__ __forceinline__ float4v mfma16(short8 a, short8 b, float4v c) {
  return __builtin_amdgcn_mfma_f32_16x16x32_bf16(a, b, c, 0, 0, 0);
}
// async global->LDS, 16B per lane; LDS dest is wave-uniform base + lane*16
__device__ __forceinline__ void gll16(const void* g, void* l) {
  __builtin_amdgcn_global_load_lds((const __attribute__((address_space(1))) void*)g,
                                   (__attribute__((address_space(3))) void*)l, 16, 0, 0);
}

// ---------------------------------------------------------------------------
// K1: dtype conversions.
// ---------------------------------------------------------------------------
__global__ __launch_bounds__(256) void convert_kernel(
    const float* __restrict__ x, const float* __restrict__ Wq,
    const float* __restrict__ Wk, const float* __restrict__ Wv,
    const float* __restrict__ Wve, const float* __restrict__ Wo,
    const float* __restrict__ Woe, u16* __restrict__ xb,
    u16* __restrict__ Wcat, u16* __restrict__ Woe_b, u16* __restrict__ Wo_b) {
  const int idx = blockIdx.x * 256 + threadIdx.x;
  const int stride = gridDim.x * 256;
  for (int i = idx; i < 2048 * 1024; i += stride) {
    const int row = i >> 10, e = i & 1023;
    const int b = row >> 8, n = row & 255;
    xb[i] = f2b(x[((size_t)n * 8 + b) * 1024 + e]);
  }
  for (int i = idx; i < 1024 * 1024; i += stride) {
    Wcat[i] = f2b(Wq[i]);
    Wcat[1048576 + i] = f2b(Wk[i]);
    Wcat[2097152 + i] = f2b(Wv[i]);
    Wcat[3145728 + i] = f2b(Wve[i]);
    Woe_b[i] = f2b(Woe[i]);
    Wo_b[i] = f2b(Wo[i]);
  }
}

// ---------------------------------------------------------------------------
// MFMA bf16 GEMM, C[M,N] f32 = A[M,K] @ W[N,K]^T (bf16 row-major).
// 128x128 tile / block. W selected per row-tile (merged epilogue GEMMs).
// ---------------------------------------------------------------------------
__global__ __launch_bounds__(256) void gemm_bt(
    const u16* __restrict__ A, const u16* __restrict__ W_lo,
    const u16* __restrict__ W_hi, int split_row, float* __restrict__ C,
    int Ndim, int Kdim) {
  __shared__ __align__(16) u16 sA[128 * 32];
  __shared__ __align__(16) u16 sB[128 * 32];
  const int tid = threadIdx.x, wave = tid >> 6, lane = tid & 63;
  const int quad = lane >> 4, l15 = lane & 15;
  const int row0 = blockIdx.y * 128, col0 = blockIdx.x * 128;
  const u16* W = (row0 < split_row) ? W_lo : W_hi;
  const int wr = (wave >> 1) * 64, wc = (wave & 1) * 64;
  const int sr = lane >> 2, sc = lane & 3;
  float4v acc[4][4] = {};
  const u16* gA = A + (size_t)row0 * Kdim;
  const u16* gW = W + (size_t)col0 * Kdim;
  for (int k0 = 0; k0 < Kdim; k0 += 32) {
    __syncthreads();
#pragma unroll
    for (int i = 0; i < 2; ++i) {
      const int r = wave * 32 + i * 16 + sr;
      gll16(gA + (size_t)r * Kdim + k0 + sc * 8, (char*)sA + (wave * 32 + i * 16) * 64);
      gll16(gW + (size_t)r * Kdim + k0 + sc * 8, (char*)sB + (wave * 32 + i * 16) * 64);
    }
    __syncthreads();
    short8 af[4], bf[4];
#pragma unroll
    for (int t = 0; t < 4; ++t) {
      af[t] = *(const short8*)(sA + (wr + t * 16 + l15) * 32 + quad * 8);
      bf[t] = *(const short8*)(sB + (wc + t * 16 + l15) * 32 + quad * 8);
    }
#pragma unroll
    for (int tm = 0; tm < 4; ++tm)
#pragma unroll
      for (int tn = 0; tn < 4; ++tn)
        acc[tm][tn] = mfma16(af[tm], bf[tn], acc[tm][tn]);
  }
#pragma unroll
  for (int tm = 0; tm < 4; ++tm)
#pragma unroll
    for (int tn = 0; tn < 4; ++tn)
#pragma unroll
      for (int r = 0; r < 4; ++r) {
        const int row = row0 + wr + tm * 16 + quad * 4 + r;
        const int col = col0 + wc + tn * 16 + l15;
        C[(size_t)row * Ndim + col] = acc[tm][tn][r];
      }
}

// ---------------------------------------------------------------------------
// K3: build per-head bf16 operands from proj [2048][4096] f32.
// ---------------------------------------------------------------------------
__global__ __launch_bounds__(256) void shuffle_kernel(
    const float* __restrict__ proj, const int* __restrict__ outcell,
    u16* __restrict__ qrow, u16* __restrict__ kext,
    u16* __restrict__ vTx, u16* __restrict__ veTx) {
  __shared__ float lds[32 * 129];
  const int mt = blockIdx.x, h = blockIdx.y, b = blockIdx.z;
  const int tid = threadIdx.x;
  const int bh = b * 32 + h;
#pragma unroll 4
  for (int i = 0; i < 16; ++i) {
    const int idx = tid + 256 * i;  // [128 m][32 d]
    const int ml = idx >> 5, d = idx & 31;
    const int m = mt * 128 + ml;
    const int src = (m < 256) ? m : outcell[b * 512 + m - 256];
    const size_t prow = ((size_t)b * 256 + src) * 4096;
    kext[((size_t)bh * 768 + m) * 32 + d] = f2b(proj[prow + 1024 + h * 32 + d]);
    if (m < 256)
      qrow[((size_t)bh * 256 + m) * 32 + d] = f2b(proj[prow + h * 32 + d] * SCALING);
  }
  for (int part = 0; part < 2; ++part) {
    const size_t cbase = (part == 0) ? 2048 : 3072;
    u16* dst = (part == 0) ? vTx : veTx;
    __syncthreads();
#pragma unroll 4
    for (int i = 0; i < 16; ++i) {
      const int idx = tid + 256 * i;
      const int ml = idx >> 5, d = idx & 31;
      const int m = mt * 128 + ml;
      const int src = (m < 256) ? m : outcell[b * 512 + m - 256];
      lds[d * 129 + ml] = proj[((size_t)b * 256 + src) * 4096 + cbase + h * 32 + d];
    }
    __syncthreads();
#pragma unroll 4
    for (int i = 0; i < 16; ++i) {
      const int idx = tid + 256 * i;
      const int d = idx >> 7, m2 = idx & 127;
      dst[((size_t)bh * 32 + d) * 768 + mt * 128 + m2] = f2b(lds[d * 129 + m2]);
    }
  }
}

// ---------------------------------------------------------------------------
// K3b: V'_c[bh][d][m] = apos[b][m][c] * vTx[bh][d][m]  (c = x,y,z).
// ---------------------------------------------------------------------------
__global__ __launch_bounds__(256) void scale_v_kernel(
    const u16* __restrict__ vTx, const float* __restrict__ pos,
    const float* __restrict__ epos, u16* __restrict__ v0,
    u16* __restrict__ v1, u16* __restrict__ v2) {
  const int bh = blockIdx.x, d = blockIdx.y, b = bh >> 5;
  const size_t base = ((size_t)bh * 32 + d) * 768;
  for (int m = threadIdx.x; m < 768; m += 256) {
    const float f = b2f((short)vTx[base + m]);
    const float* ap = (m < 256) ? (pos + ((size_t)b * 256 + m) * 3)
                                : (epos + ((size_t)b * 512 + (m - 256)) * 3);
    v0[base + m] = f2b(f * ap[0]);
    v1[base + m] = f2b(f * ap[1]);
    v2[base + m] = f2b(f * ap[2]);
  }
}

// ---------------------------------------------------------------------------
// K3c: R[b][n][m] = 1/(1 + |pos_bn - apos_bm|), bf16. Head-shared (3.1 MB).
// ---------------------------------------------------------------------------
__global__ __launch_bounds__(256) void prep_r_kernel(
    const float* __restrict__ pos, const float* __restrict__ epos,
    u16* __restrict__ R) {
  const int bn = blockIdx.x;  // 0..2047
  const int b = bn >> 8;
  const float px = pos[(size_t)bn * 3];
  const float py = pos[(size_t)bn * 3 + 1];
  const float pz = pos[(size_t)bn * 3 + 2];
  for (int m = threadIdx.x; m < 768; m += 256) {
    const float* ap = (m < 256) ? (pos + ((size_t)b * 256 + m) * 3)
                                : (epos + ((size_t)b * 512 + (m - 256)) * 3);
    const float dx = px - ap[0], dy = py - ap[1], dz = pz - ap[2];
    const float dist = __builtin_amdgcn_sqrtf(dx * dx + dy * dy + dz * dz);
    R[(size_t)bn * 768 + m] = f2b(__builtin_amdgcn_rcpf(1.0f + dist));
  }
}

// ---------------------------------------------------------------------------
// K4: fused attention. Grid (2, 256): 128 q-rows/block, 4 waves, each wave
// owns rows {grpA: w*16, grpB: 64+w*16} (+n0). Per 64-col k-tile:
// barrier -> stage (10 gll16/wave; V*/R sources pre-swizzled unit^=row&7,
// linear LDS dest) + bias->regs -> barrier -> compute grpA then grpB
// (two 32-col halves each; reads apply the same XOR; sPT reused serially).
// LDS 45KB; 2 blocks/CU; per-CU drains 24 (vs R8's 48); B-frag reads
// bank-conflict-free.
// ---------------------------------------------------------------------------
__global__ __launch_bounds__(256) void fused_attn(
    const u16* __restrict__ qrow, const u16* __restrict__ kext,
    const u16* __restrict__ vTx, const u16* __restrict__ veTx,
    const u16* __restrict__ v0Tx, const u16* __restrict__ v1Tx,
    const u16* __restrict__ v2Tx, const u16* __restrict__ Rmat,
    const float* __restrict__ bias, const float* __restrict__ pos,
    u16* __restrict__ xo_acc, u16* __restrict__ vec_acc) {
  __shared__ __align__(16) u16 sK[64 * 32];    // [k_local][d], 64B rows
  __shared__ __align__(16) u16 sV[32 * 64];    // [d][m_local], swizzled units
  __shared__ __align__(16) u16 sVe[32 * 64];
  __shared__ __align__(16) u16 sV0[32 * 64];
  __shared__ __align__(16) u16 sV1[32 * 64];
  __shared__ __align__(16) u16 sV2[32 * 64];
  __shared__ __align__(16) u16 sR[128 * 64];   // [n_local][m_local], swizzled
  __shared__ __align__(16) u16 sPT[4 * 16 * 40];
  const int nt = blockIdx.x, bh = blockIdx.y, b = bh >> 5, h = bh & 31;
  const int n0 = nt * 128;
  const int tid = threadIdx.x, w = tid >> 6, lane = tid & 63;
  const int quad = lane >> 4, l15 = lane & 15;
  const int sl = lane >> 2, sc8 = (lane & 3) * 8;       // 16-row (64B) staging
  const int el = lane >> 3;                             // 8-row (128B) staging
  const int exc = (((lane & 7) ^ el) << 3);             // swizzled src col
  const int l7x = l15 & 7;                              // read-side xor key
  // Q fragments for both row-groups (16B/lane, coalesced)
  const short8 qfA =
      *(const short8*)(qrow + ((size_t)bh * 256 + n0 + w * 16 + l15) * 32 + quad * 8);
  const short8 qfB =
      *(const short8*)(qrow + ((size_t)bh * 256 + n0 + 64 + w * 16 + l15) * 32 + quad * 8);
  float4v aeA[2] = {}, avA[2] = {}, acA0[2] = {}, acA1[2] = {}, acA2[2] = {};
  float4v aeB[2] = {}, avB[2] = {}, acB0[2] = {}, acB1[2] = {}, acB2[2] = {};
  float rsA[4] = {0.f, 0.f, 0.f, 0.f}, rsB[4] = {0.f, 0.f, 0.f, 0.f};
  const u16* gK = kext + (size_t)bh * (768 * 32);
  const u16* gV = vTx + (size_t)bh * (32 * 768);
  const u16* gVe = veTx + (size_t)bh * (32 * 768);
  const u16* gV0 = v0Tx + (size_t)bh * (32 * 768);
  const u16* gV1 = v1Tx + (size_t)bh * (32 * 768);
  const u16* gV2 = v2Tx + (size_t)bh * (32 * 768);
  const u16* gR = Rmat + ((size_t)b * 256 + n0) * 768;
  const float* gB = bias + ((size_t)bh * 256 + n0) * 768;
  u16* const pt = sPT + w * 640;  // 16 rows x 40 u16, wave-private

// stage one 8-row chunk of a 64-col tile (swizzled source, linear dest)
#define SW(GSRC, ROW0, DST, OFF)                                               \
  gll16((GSRC) + (size_t)((ROW0) + el) * 768 + k0 + exc, (char*)(DST) + (OFF))

#define BLOADG(BB, ROFF)                                                       \
  {                                                                            \
    _Pragma("unroll") for (int r = 0; r < 4; ++r) {                            \
      const float* bp = gB + (size_t)((ROFF) + w * 16 + quad * 4 + r) * 768 + k0;\
      BB[r][0] = bp[l15];                                                      \
      BB[r][1] = bp[16 + l15];                                                 \
      BB[r][2] = bp[32 + l15];                                                 \
      BB[r][3] = bp[48 + l15];                                                 \
    }                                                                          \
  }

// compute one row-group over the staged 64-col tile (two 32-col halves)
#define CGRP(QF, BB, RBASE, AE, AV, AC0, AC1, AC2, RS)                         \
  {                                                                            \
    _Pragma("unroll") for (int hh = 0; hh < 2; ++hh) {                         \
      const short8 kf0 = *(const short8*)(sK + (hh * 32 + l15) * 32 + quad * 8);\
      const short8 kf1 =                                                       \
          *(const short8*)(sK + (hh * 32 + 16 + l15) * 32 + quad * 8);         \
      float4v z = {0.f, 0.f, 0.f, 0.f};                                        \
      const float4v s0 = mfma16(QF, kf0, z);                                   \
      const float4v s1 = mfma16(QF, kf1, z);                                   \
      _Pragma("unroll") for (int r = 0; r < 4; ++r) {                          \
        const int row = quad * 4 + r;                                          \
        const float p0 = exp2f((s0[r] + BB[r][2 * hh]) * LOG2E);               \
        const float p1 = exp2f((s1[r] + BB[r][2 * hh + 1]) * LOG2E);           \
        RS[r] += p0 + p1;                                                      \
        pt[row * 40 + l15] = f2b(p0);                                          \
        pt[row * 40 + 16 + l15] = f2b(p1);                                     \
      }                                                                        \
      const short8 pf = *(const short8*)(pt + l15 * 40 + quad * 8);            \
      const int xu = (((hh * 4 + quad) ^ l7x) << 3);                           \
      const short8 rf = *(const short8*)(sR + ((RBASE) + l15) * 64 + xu);      \
      short8 prf;                                                              \
      _Pragma("unroll") for (int j = 0; j < 8; ++j)                            \
          prf[j] = (short)f2b(b2f(pf[j]) * b2f(rf[j]));                        \
      _Pragma("unroll") for (int dt = 0; dt < 2; ++dt) {                       \
        const int off = (dt * 16 + l15) * 64 + xu;                             \
        const short8 be = *(const short8*)(sVe + off);                         \
        AE[dt] = mfma16(pf, be, AE[dt]);                                       \
        const short8 bv = *(const short8*)(sV + off);                          \
        AV[dt] = mfma16(prf, bv, AV[dt]);                                      \
        const short8 c0 = *(const short8*)(sV0 + off);                         \
        AC0[dt] = mfma16(prf, c0, AC0[dt]);                                    \
        const short8 c1 = *(const short8*)(sV1 + off);                         \
        AC1[dt] = mfma16(prf, c1, AC1[dt]);                                    \
        const short8 c2 = *(const short8*)(sV2 + off);                         \
        AC2[dt] = mfma16(prf, c2, AC2[dt]);                                    \
      }                                                                        \
    }                                                                          \
  }

  for (int k0 = 0; k0 < 768; k0 += 64) {
    __syncthreads();
    if (w == 0) {
      // sK: 4 x 16 k-rows (unswizzled, 64B rows)
      gll16(gK + (size_t)(k0 + sl) * 32 + sc8, (char*)sK);
      gll16(gK + (size_t)(k0 + 16 + sl) * 32 + sc8, (char*)sK + 1024);
      gll16(gK + (size_t)(k0 + 32 + sl) * 32 + sc8, (char*)sK + 2048);
      gll16(gK + (size_t)(k0 + 48 + sl) * 32 + sc8, (char*)sK + 3072);
      SW(gV, 0, sV, 0); SW(gV, 8, sV, 1024); SW(gV, 16, sV, 2048); SW(gV, 24, sV, 3072);
      SW(gR, 0, sR, 0); SW(gR, 8, sR, 1024);
    } else if (w == 1) {
      SW(gVe, 0, sVe, 0); SW(gVe, 8, sVe, 1024); SW(gVe, 16, sVe, 2048); SW(gVe, 24, sVe, 3072);
      SW(gV0, 0, sV0, 0); SW(gV0, 8, sV0, 1024); SW(gV0, 16, sV0, 2048); SW(gV0, 24, sV0, 3072);
      SW(gR, 16, sR, 2048); SW(gR, 24, sR, 3072);
    } else if (w == 2) {
      SW(gV1, 0, sV1, 0); SW(gV1, 8, sV1, 1024); SW(gV1, 16, sV1, 2048); SW(gV1, 24, sV1, 3072);
      SW(gV2, 0, sV2, 0); SW(gV2, 8, sV2, 1024); SW(gV2, 16, sV2, 2048); SW(gV2, 24, sV2, 3072);
      SW(gR, 32, sR, 4096); SW(gR, 40, sR, 5120);
    } else {
      SW(gR, 48, sR, 6144);  SW(gR, 56, sR, 7168);
      SW(gR, 64, sR, 8192);  SW(gR, 72, sR, 9216);
      SW(gR, 80, sR, 10240); SW(gR, 88, sR, 11264);
      SW(gR, 96, sR, 12288); SW(gR, 104, sR, 13312);
      SW(gR, 112, sR, 14336); SW(gR, 120, sR, 15360);
    }
    float bbA[4][4], bbB[4][4];
    BLOADG(bbA, 0);
    BLOADG(bbB, 64);
    __syncthreads();
    CGRP(qfA, bbA, w * 16, aeA, avA, acA0, acA1, acA2, rsA);
    CGRP(qfB, bbB, 64 + w * 16, aeB, avB, acB0, acB1, acB2, rsB);
  }
#undef SW
#undef BLOADG
#undef CGRP

// epilogue per row-group
#define EPI(AE, AV, AC0, AC1, AC2, RS, ROFF)                                   \
  {                                                                            \
    float li[4];                                                               \
    _Pragma("unroll") for (int r = 0; r < 4; ++r) {                            \
      float s = RS[r];                                                         \
      _Pragma("unroll") for (int msk = 1; msk < 16; msk <<= 1)                 \
          s += __shfl_xor(s, msk, 64);                                         \
      li[r] = __builtin_amdgcn_rcpf(s);                                        \
    }                                                                          \
    _Pragma("unroll") for (int r = 0; r < 4; ++r) {                            \
      const int row = n0 + (ROFF) + w * 16 + quad * 4 + r;                     \
      const size_t prow = ((size_t)b * 256 + row) * 3;                         \
      const float pxr = pos[prow], pyr = pos[prow + 1], pzr = pos[prow + 2];   \
      _Pragma("unroll") for (int dt = 0; dt < 2; ++dt) {                       \
        const int col = dt * 16 + l15;                                         \
        xo_acc[((size_t)b * 256 + row) * 1024 + h * 32 + col] =                \
            f2b(AE[dt][r] * li[r]);                                            \
        const float vx = (pxr * AV[dt][r] - AC0[dt][r]) * li[r];               \
        const float vy = (pyr * AV[dt][r] - AC1[dt][r]) * li[r];               \
        const float vz = (pzr * AV[dt][r] - AC2[dt][r]) * li[r];               \
        vec_acc[(prow + 0) * 1024 + h * 32 + col] = f2b(vx);                   \
        vec_acc[(prow + 1) * 1024 + h * 32 + col] = f2b(vy);                   \
        vec_acc[(prow + 2) * 1024 + h * 32 + col] = f2b(vz);                   \
      }                                                                        \
    }                                                                          \
  }
  EPI(aeA, avA, acA0, acA1, acA2, rsA, 0);
  EPI(aeB, avB, acB0, acB1, acB2, rsB, 64);
#undef EPI
}

// ---------------------------------------------------------------------------
// Workspace layout (bytes). Footprint unchanged (109,051,904 B):
// V'0 aliases xb+Wcat (dead after proj GEMM); V'1/V'2/R alias proj (dead
// after shuffle). scale_v/prep_r therefore launch AFTER shuffle.
// ---------------------------------------------------------------------------
static constexpr size_t OFF_XB = 0;                          // 2048*1024*2
static constexpr size_t OFF_WCAT = OFF_XB + 4194304;         // 4096*1024*2
static constexpr size_t OFF_WOEB = OFF_WCAT + 8388608;       // 1024*1024*2
static constexpr size_t OFF_WOB = OFF_WOEB + 2097152;        // 1024*1024*2
static constexpr size_t OFF_PROJ = OFF_WOB + 2097152;        // 2048*4096*4
static constexpr size_t OFF_QROW = OFF_PROJ + 33554432;      // 256bh*256*32*2
static constexpr size_t OFF_KEXT = OFF_QROW + 4194304;       // 256bh*768*32*2
static constexpr size_t OFF_VTX = OFF_KEXT + 12582912;
static constexpr size_t OFF_VETX = OFF_VTX + 12582912;
static constexpr size_t OFF_XOACC = OFF_VETX + 12582912;     // 2048*1024*2
static constexpr size_t OFF_VECACC = OFF_XOACC + 4194304;    // 6144*1024*2
// aliased regions:
static constexpr size_t OFF_V0 = OFF_XB;                     // 12,582,912
static constexpr size_t OFF_V1 = OFF_PROJ;                   // 12,582,912
static constexpr size_t OFF_V2 = OFF_PROJ + 12582912;        // 12,582,912
static constexpr size_t OFF_R = OFF_PROJ + 25165824;         // 2048*768*2

extern "C" void kernel_launch(void* const* d_in, const int* in_sizes, int n_in,
                              void* d_out, int out_size, void* d_ws, size_t ws_size,
                              hipStream_t stream) {
  const float* x = (const float*)d_in[0];
  const float* pos = (const float*)d_in[1];
  const float* epos = (const float*)d_in[2];
  const float* bias = (const float*)d_in[3];
  const int* outcell = (const int*)d_in[6];
  const float* Wq = (const float*)d_in[7];
  const float* Wk = (const float*)d_in[8];
  const float* Wv = (const float*)d_in[9];
  const float* Wve = (const float*)d_in[10];
  const float* Wo = (const float*)d_in[11];
  const float* Woe = (const float*)d_in[12];
  char* ws = (char*)d_ws;
  u16* xb = (u16*)(ws + OFF_XB);
  u16* Wcat = (u16*)(ws + OFF_WCAT);
  u16* Woe_b = (u16*)(ws + OFF_WOEB);
  u16* Wo_b = (u16*)(ws + OFF_WOB);
  float* proj = (float*)(ws + OFF_PROJ);
  u16* qrow = (u16*)(ws + OFF_QROW);
  u16* kext = (u16*)(ws + OFF_KEXT);
  u16* vTx = (u16*)(ws + OFF_VTX);
  u16* veTx = (u16*)(ws + OFF_VETX);
  u16* v0 = (u16*)(ws + OFF_V0);
  u16* v1 = (u16*)(ws + OFF_V1);
  u16* v2 = (u16*)(ws + OFF_V2);
  u16* Rm = (u16*)(ws + OFF_R);
  u16* xo_acc = (u16*)(ws + OFF_XOACC);
  u16* vec_acc = (u16*)(ws + OFF_VECACC);
  float* out = (float*)d_out;

  convert_kernel<<<1024, 256, 0, stream>>>(x, Wq, Wk, Wv, Wve, Wo, Woe,
                                           xb, Wcat, Woe_b, Wo_b);
  gemm_bt<<<dim3(32, 16), 256, 0, stream>>>(xb, Wcat, Wcat, 1 << 30, proj, 4096, 1024);
  shuffle_kernel<<<dim3(6, 32, 8), 256, 0, stream>>>(proj, outcell, qrow, kext, vTx, veTx);
  scale_v_kernel<<<dim3(256, 32), 256, 0, stream>>>(vTx, pos, epos, v0, v1, v2);
  prep_r_kernel<<<2048, 256, 0, stream>>>(pos, epos, Rm);
  fused_attn<<<dim3(2, 256), 256, 0, stream>>>(qrow, kext, vTx, veTx, v0, v1, v2,
                                               Rm, bias, pos, xo_acc, vec_acc);
  gemm_bt<<<dim3(8, 64), 256, 0, stream>>>(xo_acc, Woe_b, Wo_b, 2048, out, 1024, 1024);
}